// Round 3
// baseline (967.019 us; speedup 1.0000x reference)
//
#include <hip/hip_runtime.h>

#define DI __device__ __forceinline__

DI float silu_f(float x) { return x / (1.f + __expf(-x)); }
DI float sigmoid_f(float x) { return 1.f / (1.f + __expf(-x)); }
DI int reflect_i(int i, int n) { if (i < 0) i = -i; if (i >= n) i = 2 * n - 2 - i; return i; }

// K1: bilinear resize (2,3,1024,1024) -> (2,3,256,256), align-corners style
__global__ void k_resize(const float* __restrict__ img, float* __restrict__ x) {
    int idx = blockIdx.x * blockDim.x + threadIdx.x;
    if (idx >= 2 * 3 * 256 * 256) return;
    int ox = idx & 255;
    int oy = (idx >> 8) & 255;
    int bc = idx >> 16;  // [0,6)
    float py = oy * (1023.f / 255.f);
    float px = ox * (1023.f / 255.f);
    int iy0 = (int)floorf(py); if (iy0 > 1022) iy0 = 1022; float fy = py - (float)iy0;
    int ix0 = (int)floorf(px); if (ix0 > 1022) ix0 = 1022; float fx = px - (float)ix0;
    const float* p = img + (size_t)bc * 1024 * 1024;
    float a00 = p[iy0 * 1024 + ix0],       a01 = p[iy0 * 1024 + ix0 + 1];
    float a10 = p[(iy0 + 1) * 1024 + ix0], a11 = p[(iy0 + 1) * 1024 + ix0 + 1];
    float r0 = a00 + fy * (a10 - a00);  // interp along H (axis 2) first
    float r1 = a01 + fy * (a11 - a01);
    x[idx] = r0 + fx * (r1 - r0);
}

// Register-blocked 3x3 conv, reflect pad 1. Each thread: 4 consecutive out-x
// pixels x 4 output channels. Weights staged in LDS (broadcast reads).
template<int CIN, int HIN, int WIN, int COUT, int STRIDE>
__global__ __launch_bounds__(256) void k_conv(const float* __restrict__ in,
                                              const float* __restrict__ w,
                                              const float* __restrict__ bias,
                                              float* __restrict__ out) {
    constexpr int HOUT = HIN / STRIDE, WOUT = WIN / STRIDE;
    constexpr int W4 = WOUT / 4;
    constexpr int NPX4 = HOUT * W4;          // px4-units per (bb, ocg)
    constexpr int OCG = COUT / 4;
    constexpr int OCGPB = (NPX4 >= 256) ? 1 : (256 / NPX4);  // oc-groups per block
    constexpr int NOC = 4 * OCGPB;           // oc staged per block
    constexpr int XSPAN = 3 * STRIDE + 3;
    static_assert((NPX4 % 256 == 0) || (256 % NPX4 == 0), "alignment");

    __shared__ float sw[NOC * CIN * 9];
    int tid = threadIdx.x;
    int id0 = blockIdx.x * 256;
    int ocg0 = (id0 / NPX4) % OCG;
    {
        const float* src = w + (size_t)(ocg0 * 4) * CIN * 9;
        for (int i = tid; i < NOC * CIN * 9; i += 256) sw[i] = src[i];
    }
    __syncthreads();

    int id = id0 + tid;
    int ox4 = id % W4;
    int oy = (id / W4) % HOUT;
    int ocg = (id / NPX4) % OCG;
    int bb = id / (NPX4 * OCG);
    int ocl = (ocg - ocg0) * 4;

    int iy[3];
#pragma unroll
    for (int k = 0; k < 3; ++k) iy[k] = reflect_i(oy * STRIDE + k - 1, HIN);
    int xs[XSPAN];
    int xbase = ox4 * 4 * STRIDE - 1;
#pragma unroll
    for (int d = 0; d < XSPAN; ++d) xs[d] = reflect_i(xbase + d, WIN);

    float acc[4][4];
#pragma unroll
    for (int o = 0; o < 4; ++o) {
        float bv = bias[ocg * 4 + o];
#pragma unroll
        for (int p = 0; p < 4; ++p) acc[o][p] = bv;
    }

    const float* ib0 = in + (size_t)bb * CIN * HIN * WIN;
    for (int ic = 0; ic < CIN; ++ic) {
        const float* ib = ib0 + (size_t)ic * HIN * WIN;
        float t[3][XSPAN];
#pragma unroll
        for (int ky = 0; ky < 3; ++ky) {
            const float* rp = ib + iy[ky] * WIN;
#pragma unroll
            for (int d = 0; d < XSPAN; ++d) t[ky][d] = rp[xs[d]];
        }
#pragma unroll
        for (int o = 0; o < 4; ++o) {
            const float* wp = sw + ((size_t)(ocl + o) * CIN + ic) * 9;
            float wv[9];
#pragma unroll
            for (int j = 0; j < 9; ++j) wv[j] = wp[j];
#pragma unroll
            for (int p = 0; p < 4; ++p)
#pragma unroll
                for (int ky = 0; ky < 3; ++ky)
#pragma unroll
                    for (int kx = 0; kx < 3; ++kx)
                        acc[o][p] = fmaf(t[ky][p * STRIDE + kx], wv[ky * 3 + kx], acc[o][p]);
        }
    }

#pragma unroll
    for (int o = 0; o < 4; ++o)
#pragma unroll
        for (int p = 0; p < 4; ++p)
            out[(((size_t)bb * COUT + ocg * 4 + o) * HOUT + oy) * WOUT + ox4 * 4 + p] =
                silu_f(acc[o][p]);
}

// K6: fused avg-pool + concat -> feat (2,480,8,8), float4 inner reads
__global__ void k_pool(const float* __restrict__ c1, const float* __restrict__ c2,
                       const float* __restrict__ c3, const float* __restrict__ c4,
                       float* __restrict__ feat) {
    int idx = blockIdx.x * blockDim.x + threadIdx.x;
    if (idx >= 2 * 480 * 64) return;
    int x = idx & 7;
    int y = (idx >> 3) & 7;
    int fc = (idx >> 6) % 480;
    int bb = idx / (480 * 64);
    const float* src; int C, HW, k, c;
    if (fc < 32)       { src = c1; C = 32;  HW = 128; k = 16; c = fc; }
    else if (fc < 96)  { src = c2; C = 64;  HW = 64;  k = 8;  c = fc - 32; }
    else if (fc < 224) { src = c3; C = 128; HW = 32;  k = 4;  c = fc - 96; }
    else               { src = c4; C = 256; HW = 16;  k = 2;  c = fc - 224; }
    const float* p = src + ((size_t)bb * C + c) * HW * HW + (y * k) * HW + x * k;
    float s = 0.f;
    if (k >= 4) {
        for (int i = 0; i < k; ++i) {
            const float4* r4 = (const float4*)(p + i * HW);
            for (int j = 0; j < k / 4; ++j) {
                float4 q = r4[j];
                s += q.x + q.y + q.z + q.w;
            }
        }
    } else {
        for (int i = 0; i < k; ++i)
            for (int j = 0; j < k; ++j) s += p[i * HW + j];
    }
    feat[idx] = s / (float)(k * k);
}

// K7: lin1 = 3x3 reflect conv 480->128 on 8x8 + SiLU. 16 lanes per output.
__global__ void k_lin1(const float* __restrict__ feat, const float* __restrict__ w,
                       const float* __restrict__ bias, float* __restrict__ h1) {
    int gid = (blockIdx.x * blockDim.x + threadIdx.x) >> 4;
    int lane = threadIdx.x & 15;
    if (gid >= 2 * 128 * 8 * 8) return;
    int ox = gid & 7;
    int oy = (gid >> 3) & 7;
    int oc = (gid >> 6) & 127;
    int bb = gid >> 13;
    const float* fp = feat + (size_t)bb * 480 * 64;
    const float* wp = w + (size_t)oc * 480 * 9;
    int iy[3], ix[3];
#pragma unroll
    for (int k = 0; k < 3; ++k) {
        iy[k] = reflect_i(oy + k - 1, 8);
        ix[k] = reflect_i(ox + k - 1, 8);
    }
    float sum = 0.f;
    for (int ic = lane; ic < 480; ic += 16) {
        const float* fpc = fp + ic * 64;
        const float* wpc = wp + ic * 9;
#pragma unroll
        for (int ky = 0; ky < 3; ++ky) {
#pragma unroll
            for (int kx = 0; kx < 3; ++kx) {
                sum = fmaf(fpc[iy[ky] * 8 + ix[kx]], wpc[ky * 3 + kx], sum);
            }
        }
    }
    sum += __shfl_xor(sum, 8, 64);
    sum += __shfl_xor(sum, 4, 64);
    sum += __shfl_xor(sum, 2, 64);
    sum += __shfl_xor(sum, 1, 64);
    if (lane == 0) h1[gid] = silu_f(sum + bias[oc]);
}

// K8: lin2 = 1x1 conv 128->27 + sigmoid -> wl (2,27,8,8)
__global__ void k_lin2(const float* __restrict__ h1, const float* __restrict__ w,
                       const float* __restrict__ bias, float* __restrict__ wl) {
    int idx = blockIdx.x * blockDim.x + threadIdx.x;
    if (idx >= 2 * 27 * 64) return;
    int pix = idx & 63;
    int oc = (idx >> 6) % 27;
    int bb = idx / (27 * 64);
    const float* hp = h1 + (size_t)bb * 128 * 64 + pix;
    const float* wp = w + oc * 128;
    float sum = bias[oc];
    for (int ic = 0; ic < 128; ++ic) sum = fmaf(hp[ic * 64], wp[ic], sum);
    wl[((size_t)bb * 27 + oc) * 64 + pix] = sigmoid_f(sum);
}

// K9: fused bilinear-upsample of wl + LUT interp + weighted sum + clip.
// Block = (bb,c) x 8 rows. Per row: y-interp of wl hoisted into su[9][8].
// Thread handles 4 consecutive px (float4 in/out).
__global__ __launch_bounds__(256) void k_apply(const float* __restrict__ img,
                                               const float* __restrict__ wl,
                                               const float* __restrict__ luts,
                                               float* __restrict__ out) {
    __shared__ float slut[9 * 256];
    __shared__ float swl[9 * 64];
    __shared__ float su[9 * 8];
    int tid = threadIdx.x;
    int bc = blockIdx.y;         // 0..5
    int bb = bc / 3, c = bc % 3;
    for (int i = tid; i < 9 * 256; i += 256) slut[i] = luts[c * 9 * 256 + i];
    for (int i = tid; i < 9 * 64; i += 256) swl[i] = wl[((size_t)bb * 27 + c * 9) * 64 + i];

    const size_t plane = (((size_t)bb * 3 + c) * 1024);
    int x0 = tid * 4;
    float fx[4]; int ix0[4];
#pragma unroll
    for (int p = 0; p < 4; ++p) {
        float pxf = (x0 + p) * (7.f / 1023.f);
        int i = (int)pxf; if (i > 6) i = 6;
        ix0[p] = i; fx[p] = pxf - (float)i;
    }

    for (int rr = 0; rr < 8; ++rr) {
        int h = blockIdx.x * 8 + rr;
        float py = h * (7.f / 1023.f);
        int iy0 = (int)py; if (iy0 > 6) iy0 = 6;
        float fy = py - (float)iy0;
        __syncthreads();  // prev row done reading su (and staging done on rr==0)
        if (tid < 72) {
            int k = tid >> 3, ixx = tid & 7;
            float s0 = swl[k * 64 + iy0 * 8 + ixx];
            float s1 = swl[k * 64 + iy0 * 8 + 8 + ixx];
            su[tid] = fmaf(fy, s1 - s0, s0);
        }
        __syncthreads();

        size_t base = (plane + h) * 1024;
        float4 v = ((const float4*)(img + base))[tid];
        float xin[4] = {v.x, v.y, v.z, v.w};
        float o[4];
#pragma unroll
        for (int p = 0; p < 4; ++p) {
            float pv = fminf(fmaxf(xin[p], 0.f), 1.f) * 255.f;
            int i0 = (int)pv; if (i0 > 254) i0 = 254;
            float fr = pv - (float)i0;
            float acc = 0.f;
#pragma unroll
            for (int k = 0; k < 9; ++k) {
                float s0 = su[k * 8 + ix0[p]];
                float s1 = su[k * 8 + ix0[p] + 1];
                float wt = fmaf(fx[p], s1 - s0, s0);
                float l0 = slut[k * 256 + i0];
                float l1 = slut[k * 256 + i0 + 1];
                acc = fmaf(wt, fmaf(fr, l1 - l0, l0), acc);
            }
            o[p] = fminf(fmaxf(acc, 0.f), 1.f);
        }
        ((float4*)(out + base))[tid] = make_float4(o[0], o[1], o[2], o[3]);
    }
}

extern "C" void kernel_launch(void* const* d_in, const int* in_sizes, int n_in,
                              void* d_out, int out_size, void* d_ws, size_t ws_size,
                              hipStream_t stream) {
    const float* img     = (const float*)d_in[0];
    const float* conv1_w = (const float*)d_in[1];
    const float* conv1_b = (const float*)d_in[2];
    const float* conv2_w = (const float*)d_in[3];
    const float* conv2_b = (const float*)d_in[4];
    const float* conv3_w = (const float*)d_in[5];
    const float* conv3_b = (const float*)d_in[6];
    const float* conv4_w = (const float*)d_in[7];
    const float* conv4_b = (const float*)d_in[8];
    const float* lin1_w  = (const float*)d_in[9];
    const float* lin1_b  = (const float*)d_in[10];
    const float* lin2_w  = (const float*)d_in[11];
    const float* lin2_b  = (const float*)d_in[12];
    const float* luts    = (const float*)d_in[13];
    float* out = (float*)d_out;

    float* ws = (float*)d_ws;
    float* x_rs = ws;            ws += 2 * 3 * 256 * 256;
    float* c1   = ws;            ws += 2 * 32 * 128 * 128;
    float* c2   = ws;            ws += 2 * 64 * 64 * 64;
    float* c3   = ws;            ws += 2 * 128 * 32 * 32;
    float* c4   = ws;            ws += 2 * 256 * 16 * 16;
    float* feat = ws;            ws += 2 * 480 * 8 * 8;
    float* h1   = ws;            ws += 2 * 128 * 8 * 8;
    float* wl   = ws;            ws += 2 * 27 * 8 * 8;

    const int B = 256;
    k_resize<<<(2 * 3 * 256 * 256 + B - 1) / B, B, 0, stream>>>(img, x_rs);
    // threads = 2 * (COUT/4) * (HOUT * WOUT/4)
    k_conv<3, 256, 256, 32, 2><<<2 * 8 * 4096 / B, B, 0, stream>>>(x_rs, conv1_w, conv1_b, c1);
    k_conv<32, 128, 128, 64, 2><<<2 * 16 * 1024 / B, B, 0, stream>>>(c1, conv2_w, conv2_b, c2);
    k_conv<64, 64, 64, 128, 2><<<2 * 32 * 256 / B, B, 0, stream>>>(c2, conv3_w, conv3_b, c3);
    k_conv<128, 32, 32, 256, 2><<<2 * 64 * 64 / B, B, 0, stream>>>(c3, conv4_w, conv4_b, c4);
    k_pool<<<(2 * 480 * 64 + B - 1) / B, B, 0, stream>>>(c1, c2, c3, c4, feat);
    k_lin1<<<(2 * 128 * 64 * 16 + B - 1) / B, B, 0, stream>>>(feat, lin1_w, lin1_b, h1);
    k_lin2<<<(2 * 27 * 64 + B - 1) / B, B, 0, stream>>>(h1, lin2_w, lin2_b, wl);
    dim3 agrid(128, 6);
    k_apply<<<agrid, B, 0, stream>>>(img, wl, luts, out);
}

// Round 4
// 415.871 us; speedup vs baseline: 2.3253x; 2.3253x over previous
//
#include <hip/hip_runtime.h>

#define DI __device__ __forceinline__

DI float silu_f(float x) { return x / (1.f + __expf(-x)); }
DI float sigmoid_f(float x) { return 1.f / (1.f + __expf(-x)); }
DI int reflect_i(int i, int n) { if (i < 0) i = -i; if (i >= n) i = 2 * n - 2 - i; return i; }

// K1: bilinear resize (2,3,1024,1024) -> (2,3,256,256), align-corners style
__global__ void k_resize(const float* __restrict__ img, float* __restrict__ x) {
    int idx = blockIdx.x * blockDim.x + threadIdx.x;
    if (idx >= 2 * 3 * 256 * 256) return;
    int ox = idx & 255;
    int oy = (idx >> 8) & 255;
    int bc = idx >> 16;  // [0,6)
    float py = oy * (1023.f / 255.f);
    float px = ox * (1023.f / 255.f);
    int iy0 = (int)floorf(py); if (iy0 > 1022) iy0 = 1022; float fy = py - (float)iy0;
    int ix0 = (int)floorf(px); if (ix0 > 1022) ix0 = 1022; float fx = px - (float)ix0;
    const float* p = img + (size_t)bc * 1024 * 1024;
    float a00 = p[iy0 * 1024 + ix0],       a01 = p[iy0 * 1024 + ix0 + 1];
    float a10 = p[(iy0 + 1) * 1024 + ix0], a11 = p[(iy0 + 1) * 1024 + ix0 + 1];
    float r0 = a00 + fy * (a10 - a00);  // interp along H (axis 2) first
    float r1 = a01 + fy * (a11 - a01);
    x[idx] = r0 + fx * (r1 - r0);
}

// 3x3 stride-2 reflect conv + SiLU.
// Thread = PX_PER out-x pixels x OC_PER ocs x 1/KC of the Cin range.
// kc lives in the LOW lane bits -> partials reduced with shfl_xor(1[,2]).
// Block covers OC_PER ocs (weights in LDS) and 256/KC px-units.
template<int CIN, int HIN, int WIN, int COUT, int PX_PER, int OC_PER, int KC>
__global__ __launch_bounds__(256) void k_conv(const float* __restrict__ in,
                                              const float* __restrict__ w,
                                              const float* __restrict__ bias,
                                              float* __restrict__ out) {
    constexpr int HOUT = HIN / 2, WOUT = WIN / 2;
    constexpr int W_U = WOUT / PX_PER;
    constexpr int NPXU = 2 * HOUT * W_U;       // px-units total (B=2)
    constexpr int PXPB = 256 / KC;             // px-units per block
    constexpr int NB_PX = NPXU / PXPB;
    constexpr int ICC = CIN / KC;              // ic per k-chunk
    constexpr int XSPAN = 2 * PX_PER + 1;

    __shared__ float sw[OC_PER * CIN * 9];
    const int tid = threadIdx.x;
    const int ocu = blockIdx.x / NB_PX;
    const int bpx = blockIdx.x % NB_PX;
    {
        const float* src = w + (size_t)(ocu * OC_PER) * CIN * 9;
        for (int i = tid; i < OC_PER * CIN * 9; i += 256) sw[i] = src[i];
    }
    __syncthreads();

    const int kc  = (KC > 1) ? (tid % KC) : 0;
    const int pxl = (KC > 1) ? (tid / KC) : tid;
    const int pxu = bpx * PXPB + pxl;
    const int oxu = pxu % W_U;
    const int oy  = (pxu / W_U) % HOUT;
    const int bb  = pxu / (W_U * HOUT);
    const int ox0 = oxu * PX_PER;

    int iy[3];
#pragma unroll
    for (int k = 0; k < 3; ++k) iy[k] = reflect_i(2 * oy + k - 1, HIN);
    int xs[XSPAN];
#pragma unroll
    for (int d = 0; d < XSPAN; ++d) xs[d] = reflect_i(2 * ox0 - 1 + d, WIN);

    float acc[OC_PER][PX_PER];
#pragma unroll
    for (int o = 0; o < OC_PER; ++o)
#pragma unroll
        for (int p = 0; p < PX_PER; ++p) acc[o][p] = 0.f;

    for (int icl = 0; icl < ICC; ++icl) {
        const int ic = kc * ICC + icl;
        const float* ib = in + ((size_t)bb * CIN + ic) * HIN * WIN;
        float t[3][XSPAN];
#pragma unroll
        for (int ky = 0; ky < 3; ++ky) {
            const float* rp = ib + iy[ky] * WIN;
#pragma unroll
            for (int d = 0; d < XSPAN; ++d) t[ky][d] = rp[xs[d]];
        }
#pragma unroll
        for (int o = 0; o < OC_PER; ++o) {
            const float* wp = sw + ((size_t)o * CIN + ic) * 9;
            float wv[9];
#pragma unroll
            for (int j = 0; j < 9; ++j) wv[j] = wp[j];
#pragma unroll
            for (int p = 0; p < PX_PER; ++p)
#pragma unroll
                for (int ky = 0; ky < 3; ++ky)
#pragma unroll
                    for (int kx = 0; kx < 3; ++kx)
                        acc[o][p] = fmaf(t[ky][2 * p + kx], wv[ky * 3 + kx], acc[o][p]);
        }
    }

    if (KC > 1) {
#pragma unroll
        for (int o = 0; o < OC_PER; ++o)
#pragma unroll
            for (int p = 0; p < PX_PER; ++p) {
                float s = acc[o][p];
                s += __shfl_xor(s, 1, 64);
                if (KC == 4) s += __shfl_xor(s, 2, 64);
                acc[o][p] = s;
            }
        if (kc < OC_PER) {
            const int o = kc;
            const int oc = ocu * OC_PER + o;
            float bv = bias[oc];
            float* op = out + (((size_t)bb * COUT + oc) * HOUT + oy) * WOUT + ox0;
#pragma unroll
            for (int p = 0; p < PX_PER; ++p) op[p] = silu_f(acc[o][p] + bv);
        }
    } else {
#pragma unroll
        for (int o = 0; o < OC_PER; ++o) {
            const int oc = ocu * OC_PER + o;
            float bv = bias[oc];
            float* op = out + (((size_t)bb * COUT + oc) * HOUT + oy) * WOUT + ox0;
            if (PX_PER == 4) {
                float4 v = make_float4(silu_f(acc[o][0] + bv), silu_f(acc[o][1] + bv),
                                       silu_f(acc[o][2] + bv), silu_f(acc[o][3] + bv));
                *(float4*)op = v;
            } else if (PX_PER == 2) {
                float2 v = make_float2(silu_f(acc[o][0] + bv), silu_f(acc[o][1] + bv));
                *(float2*)op = v;
            } else {
#pragma unroll
                for (int p = 0; p < PX_PER; ++p) op[p] = silu_f(acc[o][p] + bv);
            }
        }
    }
}

// K6: fused avg-pool + concat -> feat (2,480,8,8), float4 inner reads
__global__ void k_pool(const float* __restrict__ c1, const float* __restrict__ c2,
                       const float* __restrict__ c3, const float* __restrict__ c4,
                       float* __restrict__ feat) {
    int idx = blockIdx.x * blockDim.x + threadIdx.x;
    if (idx >= 2 * 480 * 64) return;
    int x = idx & 7;
    int y = (idx >> 3) & 7;
    int fc = (idx >> 6) % 480;
    int bb = idx / (480 * 64);
    const float* src; int C, HW, k, c;
    if (fc < 32)       { src = c1; C = 32;  HW = 128; k = 16; c = fc; }
    else if (fc < 96)  { src = c2; C = 64;  HW = 64;  k = 8;  c = fc - 32; }
    else if (fc < 224) { src = c3; C = 128; HW = 32;  k = 4;  c = fc - 96; }
    else               { src = c4; C = 256; HW = 16;  k = 2;  c = fc - 224; }
    const float* p = src + ((size_t)bb * C + c) * HW * HW + (y * k) * HW + x * k;
    float s = 0.f;
    if (k >= 4) {
        for (int i = 0; i < k; ++i) {
            const float4* r4 = (const float4*)(p + i * HW);
            for (int j = 0; j < k / 4; ++j) {
                float4 q = r4[j];
                s += q.x + q.y + q.z + q.w;
            }
        }
    } else {
        for (int i = 0; i < k; ++i)
            for (int j = 0; j < k; ++j) s += p[i * HW + j];
    }
    feat[idx] = s / (float)(k * k);
}

// K7: lin1 = 3x3 reflect conv 480->128 on 8x8 + SiLU. 16 lanes per output.
__global__ void k_lin1(const float* __restrict__ feat, const float* __restrict__ w,
                       const float* __restrict__ bias, float* __restrict__ h1) {
    int gid = (blockIdx.x * blockDim.x + threadIdx.x) >> 4;
    int lane = threadIdx.x & 15;
    if (gid >= 2 * 128 * 8 * 8) return;
    int ox = gid & 7;
    int oy = (gid >> 3) & 7;
    int oc = (gid >> 6) & 127;
    int bb = gid >> 13;
    const float* fp = feat + (size_t)bb * 480 * 64;
    const float* wp = w + (size_t)oc * 480 * 9;
    int iy[3], ix[3];
#pragma unroll
    for (int k = 0; k < 3; ++k) {
        iy[k] = reflect_i(oy + k - 1, 8);
        ix[k] = reflect_i(ox + k - 1, 8);
    }
    float sum = 0.f;
    for (int ic = lane; ic < 480; ic += 16) {
        const float* fpc = fp + ic * 64;
        const float* wpc = wp + ic * 9;
#pragma unroll
        for (int ky = 0; ky < 3; ++ky) {
#pragma unroll
            for (int kx = 0; kx < 3; ++kx) {
                sum = fmaf(fpc[iy[ky] * 8 + ix[kx]], wpc[ky * 3 + kx], sum);
            }
        }
    }
    sum += __shfl_xor(sum, 8, 64);
    sum += __shfl_xor(sum, 4, 64);
    sum += __shfl_xor(sum, 2, 64);
    sum += __shfl_xor(sum, 1, 64);
    if (lane == 0) h1[gid] = silu_f(sum + bias[oc]);
}

// K8: lin2 = 1x1 conv 128->27 + sigmoid -> wl (2,27,8,8)
__global__ void k_lin2(const float* __restrict__ h1, const float* __restrict__ w,
                       const float* __restrict__ bias, float* __restrict__ wl) {
    int idx = blockIdx.x * blockDim.x + threadIdx.x;
    if (idx >= 2 * 27 * 64) return;
    int pix = idx & 63;
    int oc = (idx >> 6) % 27;
    int bb = idx / (27 * 64);
    const float* hp = h1 + (size_t)bb * 128 * 64 + pix;
    const float* wp = w + oc * 128;
    float sum = bias[oc];
    for (int ic = 0; ic < 128; ++ic) sum = fmaf(hp[ic * 64], wp[ic], sum);
    wl[((size_t)bb * 27 + oc) * 64 + pix] = sigmoid_f(sum);
}

// K9: fused bilinear-upsample of wl + LUT interp + weighted sum + clip.
__global__ __launch_bounds__(256) void k_apply(const float* __restrict__ img,
                                               const float* __restrict__ wl,
                                               const float* __restrict__ luts,
                                               float* __restrict__ out) {
    __shared__ float slut[9 * 256];
    __shared__ float swl[9 * 64];
    __shared__ float su[9 * 8];
    int tid = threadIdx.x;
    int bc = blockIdx.y;         // 0..5
    int bb = bc / 3, c = bc % 3;
    for (int i = tid; i < 9 * 256; i += 256) slut[i] = luts[c * 9 * 256 + i];
    for (int i = tid; i < 9 * 64; i += 256) swl[i] = wl[((size_t)bb * 27 + c * 9) * 64 + i];

    const size_t plane = (((size_t)bb * 3 + c) * 1024);
    int x0 = tid * 4;
    float fx[4]; int ix0[4];
#pragma unroll
    for (int p = 0; p < 4; ++p) {
        float pxf = (x0 + p) * (7.f / 1023.f);
        int i = (int)pxf; if (i > 6) i = 6;
        ix0[p] = i; fx[p] = pxf - (float)i;
    }

    for (int rr = 0; rr < 8; ++rr) {
        int h = blockIdx.x * 8 + rr;
        float py = h * (7.f / 1023.f);
        int iy0 = (int)py; if (iy0 > 6) iy0 = 6;
        float fy = py - (float)iy0;
        __syncthreads();  // prev row done reading su (and staging done on rr==0)
        if (tid < 72) {
            int k = tid >> 3, ixx = tid & 7;
            float s0 = swl[k * 64 + iy0 * 8 + ixx];
            float s1 = swl[k * 64 + iy0 * 8 + 8 + ixx];
            su[tid] = fmaf(fy, s1 - s0, s0);
        }
        __syncthreads();

        size_t base = (plane + h) * 1024;
        float4 v = ((const float4*)(img + base))[tid];
        float xin[4] = {v.x, v.y, v.z, v.w};
        float o[4];
#pragma unroll
        for (int p = 0; p < 4; ++p) {
            float pv = fminf(fmaxf(xin[p], 0.f), 1.f) * 255.f;
            int i0 = (int)pv; if (i0 > 254) i0 = 254;
            float fr = pv - (float)i0;
            float acc = 0.f;
#pragma unroll
            for (int k = 0; k < 9; ++k) {
                float s0 = su[k * 8 + ix0[p]];
                float s1 = su[k * 8 + ix0[p] + 1];
                float wt = fmaf(fx[p], s1 - s0, s0);
                float l0 = slut[k * 256 + i0];
                float l1 = slut[k * 256 + i0 + 1];
                acc = fmaf(wt, fmaf(fr, l1 - l0, l0), acc);
            }
            o[p] = fminf(fmaxf(acc, 0.f), 1.f);
        }
        ((float4*)(out + base))[tid] = make_float4(o[0], o[1], o[2], o[3]);
    }
}

extern "C" void kernel_launch(void* const* d_in, const int* in_sizes, int n_in,
                              void* d_out, int out_size, void* d_ws, size_t ws_size,
                              hipStream_t stream) {
    const float* img     = (const float*)d_in[0];
    const float* conv1_w = (const float*)d_in[1];
    const float* conv1_b = (const float*)d_in[2];
    const float* conv2_w = (const float*)d_in[3];
    const float* conv2_b = (const float*)d_in[4];
    const float* conv3_w = (const float*)d_in[5];
    const float* conv3_b = (const float*)d_in[6];
    const float* conv4_w = (const float*)d_in[7];
    const float* conv4_b = (const float*)d_in[8];
    const float* lin1_w  = (const float*)d_in[9];
    const float* lin1_b  = (const float*)d_in[10];
    const float* lin2_w  = (const float*)d_in[11];
    const float* lin2_b  = (const float*)d_in[12];
    const float* luts    = (const float*)d_in[13];
    float* out = (float*)d_out;

    float* ws = (float*)d_ws;
    float* x_rs = ws;            ws += 2 * 3 * 256 * 256;
    float* c1   = ws;            ws += 2 * 32 * 128 * 128;
    float* c2   = ws;            ws += 2 * 64 * 64 * 64;
    float* c3   = ws;            ws += 2 * 128 * 32 * 32;
    float* c4   = ws;            ws += 2 * 256 * 16 * 16;
    float* feat = ws;            ws += 2 * 480 * 8 * 8;
    float* h1   = ws;            ws += 2 * 128 * 8 * 8;
    float* wl   = ws;            ws += 2 * 27 * 8 * 8;

    const int B = 256;
    k_resize<<<(2 * 3 * 256 * 256 + B - 1) / B, B, 0, stream>>>(img, x_rs);
    // conv1: PX4 x OC2, KC1 -> blocks = (2*128*32/256) * (32/2) = 32*16 = 512
    k_conv<3, 256, 256, 32, 4, 2, 1><<<512, B, 0, stream>>>(x_rs, conv1_w, conv1_b, c1);
    // conv2: PX2 x OC2, KC1 -> (2*64*32/256) * (64/2) = 16*32 = 512
    k_conv<32, 128, 128, 64, 2, 2, 1><<<512, B, 0, stream>>>(c1, conv2_w, conv2_b, c2);
    // conv3: PX1 x OC2, KC4 -> (2*32*32/64) * (128/2) = 32*64 = 2048
    k_conv<64, 64, 64, 128, 1, 2, 4><<<2048, B, 0, stream>>>(c2, conv3_w, conv3_b, c3);
    // conv4: PX1 x OC2, KC4 -> (2*16*16/64) * (256/2) = 8*128 = 1024
    k_conv<128, 32, 32, 256, 1, 2, 4><<<1024, B, 0, stream>>>(c3, conv4_w, conv4_b, c4);
    k_pool<<<(2 * 480 * 64 + B - 1) / B, B, 0, stream>>>(c1, c2, c3, c4, feat);
    k_lin1<<<(2 * 128 * 64 * 16 + B - 1) / B, B, 0, stream>>>(feat, lin1_w, lin1_b, h1);
    k_lin2<<<(2 * 27 * 64 + B - 1) / B, B, 0, stream>>>(h1, lin2_w, lin2_b, wl);
    dim3 agrid(128, 6);
    k_apply<<<agrid, B, 0, stream>>>(img, wl, luts, out);
}

// Round 5
// 304.385 us; speedup vs baseline: 3.1770x; 1.3663x over previous
//
#include <hip/hip_runtime.h>

#define DI __device__ __forceinline__

DI float silu_f(float x) { return x / (1.f + __expf(-x)); }
DI float sigmoid_f(float x) { return 1.f / (1.f + __expf(-x)); }
DI int reflect_i(int i, int n) { if (i < 0) i = -i; if (i >= n) i = 2 * n - 2 - i; return i; }

// K1: bilinear resize (2,3,1024,1024) -> (2,3,256,256), align-corners style
__global__ void k_resize(const float* __restrict__ img, float* __restrict__ x) {
    int idx = blockIdx.x * blockDim.x + threadIdx.x;
    if (idx >= 2 * 3 * 256 * 256) return;
    int ox = idx & 255;
    int oy = (idx >> 8) & 255;
    int bc = idx >> 16;  // [0,6)
    float py = oy * (1023.f / 255.f);
    float px = ox * (1023.f / 255.f);
    int iy0 = (int)floorf(py); if (iy0 > 1022) iy0 = 1022; float fy = py - (float)iy0;
    int ix0 = (int)floorf(px); if (ix0 > 1022) ix0 = 1022; float fx = px - (float)ix0;
    const float* p = img + (size_t)bc * 1024 * 1024;
    float a00 = p[iy0 * 1024 + ix0],       a01 = p[iy0 * 1024 + ix0 + 1];
    float a10 = p[(iy0 + 1) * 1024 + ix0], a11 = p[(iy0 + 1) * 1024 + ix0 + 1];
    float r0 = a00 + fy * (a10 - a00);  // interp along H (axis 2) first
    float r1 = a01 + fy * (a11 - a01);
    x[idx] = r0 + fx * (r1 - r0);
}

// 3x3 stride-2 reflect conv + SiLU.
// Thread = PX_PER out-x pixels x OC_PER ocs x 1/KC of the Cin range.
// kc lives in the LOW lane bits -> partials reduced with shfl_xor(1[,2]).
template<int CIN, int HIN, int WIN, int COUT, int PX_PER, int OC_PER, int KC>
__global__ __launch_bounds__(256) void k_conv(const float* __restrict__ in,
                                              const float* __restrict__ w,
                                              const float* __restrict__ bias,
                                              float* __restrict__ out) {
    constexpr int HOUT = HIN / 2, WOUT = WIN / 2;
    constexpr int W_U = WOUT / PX_PER;
    constexpr int NPXU = 2 * HOUT * W_U;       // px-units total (B=2)
    constexpr int PXPB = 256 / KC;             // px-units per block
    constexpr int NB_PX = NPXU / PXPB;
    constexpr int ICC = CIN / KC;              // ic per k-chunk
    constexpr int XSPAN = 2 * PX_PER + 1;

    __shared__ float sw[OC_PER * CIN * 9];
    const int tid = threadIdx.x;
    const int ocu = blockIdx.x / NB_PX;
    const int bpx = blockIdx.x % NB_PX;
    {
        const float* src = w + (size_t)(ocu * OC_PER) * CIN * 9;
        for (int i = tid; i < OC_PER * CIN * 9; i += 256) sw[i] = src[i];
    }
    __syncthreads();

    const int kc  = (KC > 1) ? (tid % KC) : 0;
    const int pxl = (KC > 1) ? (tid / KC) : tid;
    const int pxu = bpx * PXPB + pxl;
    const int oxu = pxu % W_U;
    const int oy  = (pxu / W_U) % HOUT;
    const int bb  = pxu / (W_U * HOUT);
    const int ox0 = oxu * PX_PER;

    int iy[3];
#pragma unroll
    for (int k = 0; k < 3; ++k) iy[k] = reflect_i(2 * oy + k - 1, HIN);
    int xs[XSPAN];
#pragma unroll
    for (int d = 0; d < XSPAN; ++d) xs[d] = reflect_i(2 * ox0 - 1 + d, WIN);

    float acc[OC_PER][PX_PER];
#pragma unroll
    for (int o = 0; o < OC_PER; ++o)
#pragma unroll
        for (int p = 0; p < PX_PER; ++p) acc[o][p] = 0.f;

    for (int icl = 0; icl < ICC; ++icl) {
        const int ic = kc * ICC + icl;
        const float* ib = in + ((size_t)bb * CIN + ic) * HIN * WIN;
        float t[3][XSPAN];
#pragma unroll
        for (int ky = 0; ky < 3; ++ky) {
            const float* rp = ib + iy[ky] * WIN;
#pragma unroll
            for (int d = 0; d < XSPAN; ++d) t[ky][d] = rp[xs[d]];
        }
#pragma unroll
        for (int o = 0; o < OC_PER; ++o) {
            const float* wp = sw + ((size_t)o * CIN + ic) * 9;
            float wv[9];
#pragma unroll
            for (int j = 0; j < 9; ++j) wv[j] = wp[j];
#pragma unroll
            for (int p = 0; p < PX_PER; ++p)
#pragma unroll
                for (int ky = 0; ky < 3; ++ky)
#pragma unroll
                    for (int kx = 0; kx < 3; ++kx)
                        acc[o][p] = fmaf(t[ky][2 * p + kx], wv[ky * 3 + kx], acc[o][p]);
        }
    }

    if (KC > 1) {
#pragma unroll
        for (int o = 0; o < OC_PER; ++o)
#pragma unroll
            for (int p = 0; p < PX_PER; ++p) {
                float s = acc[o][p];
                s += __shfl_xor(s, 1, 64);
                if (KC == 4) s += __shfl_xor(s, 2, 64);
                acc[o][p] = s;
            }
        if (kc < OC_PER) {
            const int o = kc;
            const int oc = ocu * OC_PER + o;
            float bv = bias[oc];
            float* op = out + (((size_t)bb * COUT + oc) * HOUT + oy) * WOUT + ox0;
#pragma unroll
            for (int p = 0; p < PX_PER; ++p) op[p] = silu_f(acc[o][p] + bv);
        }
    } else {
#pragma unroll
        for (int o = 0; o < OC_PER; ++o) {
            const int oc = ocu * OC_PER + o;
            float bv = bias[oc];
            float* op = out + (((size_t)bb * COUT + oc) * HOUT + oy) * WOUT + ox0;
            if (PX_PER == 4) {
                float4 v = make_float4(silu_f(acc[o][0] + bv), silu_f(acc[o][1] + bv),
                                       silu_f(acc[o][2] + bv), silu_f(acc[o][3] + bv));
                *(float4*)op = v;
            } else if (PX_PER == 2) {
                float2 v = make_float2(silu_f(acc[o][0] + bv), silu_f(acc[o][1] + bv));
                *(float2*)op = v;
            } else {
#pragma unroll
                for (int p = 0; p < PX_PER; ++p) op[p] = silu_f(acc[o][p] + bv);
            }
        }
    }
}

// K6: fused avg-pool + concat -> feat (2,480,8,8), float4 inner reads
__global__ void k_pool(const float* __restrict__ c1, const float* __restrict__ c2,
                       const float* __restrict__ c3, const float* __restrict__ c4,
                       float* __restrict__ feat) {
    int idx = blockIdx.x * blockDim.x + threadIdx.x;
    if (idx >= 2 * 480 * 64) return;
    int x = idx & 7;
    int y = (idx >> 3) & 7;
    int fc = (idx >> 6) % 480;
    int bb = idx / (480 * 64);
    const float* src; int C, HW, k, c;
    if (fc < 32)       { src = c1; C = 32;  HW = 128; k = 16; c = fc; }
    else if (fc < 96)  { src = c2; C = 64;  HW = 64;  k = 8;  c = fc - 32; }
    else if (fc < 224) { src = c3; C = 128; HW = 32;  k = 4;  c = fc - 96; }
    else               { src = c4; C = 256; HW = 16;  k = 2;  c = fc - 224; }
    const float* p = src + ((size_t)bb * C + c) * HW * HW + (y * k) * HW + x * k;
    float s = 0.f;
    if (k >= 4) {
        for (int i = 0; i < k; ++i) {
            const float4* r4 = (const float4*)(p + i * HW);
            for (int j = 0; j < k / 4; ++j) {
                float4 q = r4[j];
                s += q.x + q.y + q.z + q.w;
            }
        }
    } else {
        for (int i = 0; i < k; ++i)
            for (int j = 0; j < k; ++j) s += p[i * HW + j];
    }
    feat[idx] = s / (float)(k * k);
}

// K7: lin1 = 3x3 reflect conv 480->128 on 8x8 + SiLU.
// Block (512 thr = 8 waves) per (bb, oc). Lane = pixel; wave = 1/8 of ic range.
// Per ic: one coalesced 256B plane load; 9 reflect-taps via __shfl; weights
// (single oc) staged in LDS, wave-uniform broadcast reads.
__global__ __launch_bounds__(512) void k_lin1(const float* __restrict__ feat,
                                              const float* __restrict__ w,
                                              const float* __restrict__ bias,
                                              float* __restrict__ h1) {
    __shared__ float sw[480 * 9];
    __shared__ float sred[8][64];
    const int tid = threadIdx.x;
    const int bb = blockIdx.x >> 7;
    const int oc = blockIdx.x & 127;
    {
        const float* src = w + (size_t)oc * 480 * 9;
        for (int i = tid; i < 480 * 9; i += 512) sw[i] = src[i];
    }
    const int wave = tid >> 6;
    const int lane = tid & 63;
    const int py = lane >> 3, px = lane & 7;
    int srcl[9];
#pragma unroll
    for (int ky = 0; ky < 3; ++ky)
#pragma unroll
        for (int kx = 0; kx < 3; ++kx)
            srcl[ky * 3 + kx] = reflect_i(py + ky - 1, 8) * 8 + reflect_i(px + kx - 1, 8);
    __syncthreads();

    const float* fp = feat + (size_t)bb * 480 * 64;
    float acc = 0.f;
    for (int ic = wave * 60; ic < wave * 60 + 60; ++ic) {
        float v = fp[ic * 64 + lane];
        const float* wp = sw + ic * 9;
#pragma unroll
        for (int j = 0; j < 9; ++j)
            acc = fmaf(__shfl(v, srcl[j], 64), wp[j], acc);
    }
    sred[wave][lane] = acc;
    __syncthreads();
    if (wave == 0) {
        float s = 0.f;
#pragma unroll
        for (int wv = 0; wv < 8; ++wv) s += sred[wv][lane];
        h1[((size_t)bb * 128 + oc) * 64 + lane] = silu_f(s + bias[oc]);
    }
}

// K8: lin2 = 1x1 conv 128->27 + sigmoid -> wl (2,27,8,8)
__global__ void k_lin2(const float* __restrict__ h1, const float* __restrict__ w,
                       const float* __restrict__ bias, float* __restrict__ wl) {
    int idx = blockIdx.x * blockDim.x + threadIdx.x;
    if (idx >= 2 * 27 * 64) return;
    int pix = idx & 63;
    int oc = (idx >> 6) % 27;
    int bb = idx / (27 * 64);
    const float* hp = h1 + (size_t)bb * 128 * 64 + pix;
    const float* wp = w + oc * 128;
    float sum = bias[oc];
    for (int ic = 0; ic < 128; ++ic) sum = fmaf(hp[ic * 64], wp[ic], sum);
    wl[((size_t)bb * 27 + oc) * 64 + pix] = sigmoid_f(sum);
}

// K9: fused bilinear-upsample of wl + LUT interp + weighted sum + clip.
__global__ __launch_bounds__(256) void k_apply(const float* __restrict__ img,
                                               const float* __restrict__ wl,
                                               const float* __restrict__ luts,
                                               float* __restrict__ out) {
    __shared__ float slut[9 * 256];
    __shared__ float swl[9 * 64];
    __shared__ float su[9 * 8];
    int tid = threadIdx.x;
    int bc = blockIdx.y;         // 0..5
    int bb = bc / 3, c = bc % 3;
    for (int i = tid; i < 9 * 256; i += 256) slut[i] = luts[c * 9 * 256 + i];
    for (int i = tid; i < 9 * 64; i += 256) swl[i] = wl[((size_t)bb * 27 + c * 9) * 64 + i];

    const size_t plane = (((size_t)bb * 3 + c) * 1024);
    int x0 = tid * 4;
    float fx[4]; int ix0[4];
#pragma unroll
    for (int p = 0; p < 4; ++p) {
        float pxf = (x0 + p) * (7.f / 1023.f);
        int i = (int)pxf; if (i > 6) i = 6;
        ix0[p] = i; fx[p] = pxf - (float)i;
    }

    for (int rr = 0; rr < 8; ++rr) {
        int h = blockIdx.x * 8 + rr;
        float py = h * (7.f / 1023.f);
        int iy0 = (int)py; if (iy0 > 6) iy0 = 6;
        float fy = py - (float)iy0;
        __syncthreads();  // prev row done reading su (and staging done on rr==0)
        if (tid < 72) {
            int k = tid >> 3, ixx = tid & 7;
            float s0 = swl[k * 64 + iy0 * 8 + ixx];
            float s1 = swl[k * 64 + iy0 * 8 + 8 + ixx];
            su[tid] = fmaf(fy, s1 - s0, s0);
        }
        __syncthreads();

        size_t base = (plane + h) * 1024;
        float4 v = ((const float4*)(img + base))[tid];
        float xin[4] = {v.x, v.y, v.z, v.w};
        float o[4];
#pragma unroll
        for (int p = 0; p < 4; ++p) {
            float pv = fminf(fmaxf(xin[p], 0.f), 1.f) * 255.f;
            int i0 = (int)pv; if (i0 > 254) i0 = 254;
            float fr = pv - (float)i0;
            float acc = 0.f;
#pragma unroll
            for (int k = 0; k < 9; ++k) {
                float s0 = su[k * 8 + ix0[p]];
                float s1 = su[k * 8 + ix0[p] + 1];
                float wt = fmaf(fx[p], s1 - s0, s0);
                float l0 = slut[k * 256 + i0];
                float l1 = slut[k * 256 + i0 + 1];
                acc = fmaf(wt, fmaf(fr, l1 - l0, l0), acc);
            }
            o[p] = fminf(fmaxf(acc, 0.f), 1.f);
        }
        ((float4*)(out + base))[tid] = make_float4(o[0], o[1], o[2], o[3]);
    }
}

extern "C" void kernel_launch(void* const* d_in, const int* in_sizes, int n_in,
                              void* d_out, int out_size, void* d_ws, size_t ws_size,
                              hipStream_t stream) {
    const float* img     = (const float*)d_in[0];
    const float* conv1_w = (const float*)d_in[1];
    const float* conv1_b = (const float*)d_in[2];
    const float* conv2_w = (const float*)d_in[3];
    const float* conv2_b = (const float*)d_in[4];
    const float* conv3_w = (const float*)d_in[5];
    const float* conv3_b = (const float*)d_in[6];
    const float* conv4_w = (const float*)d_in[7];
    const float* conv4_b = (const float*)d_in[8];
    const float* lin1_w  = (const float*)d_in[9];
    const float* lin1_b  = (const float*)d_in[10];
    const float* lin2_w  = (const float*)d_in[11];
    const float* lin2_b  = (const float*)d_in[12];
    const float* luts    = (const float*)d_in[13];
    float* out = (float*)d_out;

    float* ws = (float*)d_ws;
    float* x_rs = ws;            ws += 2 * 3 * 256 * 256;
    float* c1   = ws;            ws += 2 * 32 * 128 * 128;
    float* c2   = ws;            ws += 2 * 64 * 64 * 64;
    float* c3   = ws;            ws += 2 * 128 * 32 * 32;
    float* c4   = ws;            ws += 2 * 256 * 16 * 16;
    float* feat = ws;            ws += 2 * 480 * 8 * 8;
    float* h1   = ws;            ws += 2 * 128 * 8 * 8;
    float* wl   = ws;            ws += 2 * 27 * 8 * 8;

    const int B = 256;
    k_resize<<<(2 * 3 * 256 * 256 + B - 1) / B, B, 0, stream>>>(img, x_rs);
    k_conv<3, 256, 256, 32, 4, 2, 1><<<512, B, 0, stream>>>(x_rs, conv1_w, conv1_b, c1);
    k_conv<32, 128, 128, 64, 2, 2, 1><<<512, B, 0, stream>>>(c1, conv2_w, conv2_b, c2);
    k_conv<64, 64, 64, 128, 1, 2, 4><<<2048, B, 0, stream>>>(c2, conv3_w, conv3_b, c3);
    k_conv<128, 32, 32, 256, 1, 2, 4><<<1024, B, 0, stream>>>(c3, conv4_w, conv4_b, c4);
    k_pool<<<(2 * 480 * 64 + B - 1) / B, B, 0, stream>>>(c1, c2, c3, c4, feat);
    k_lin1<<<256, 512, 0, stream>>>(feat, lin1_w, lin1_b, h1);
    k_lin2<<<(2 * 27 * 64 + B - 1) / B, B, 0, stream>>>(h1, lin2_w, lin2_b, wl);
    dim3 agrid(128, 6);
    k_apply<<<agrid, B, 0, stream>>>(img, wl, luts, out);
}

// Round 6
// 243.002 us; speedup vs baseline: 3.9795x; 1.2526x over previous
//
#include <hip/hip_runtime.h>

#define DI __device__ __forceinline__

DI float silu_f(float x) { return x / (1.f + __expf(-x)); }
DI float sigmoid_f(float x) { return 1.f / (1.f + __expf(-x)); }
DI int reflect_i(int i, int n) { if (i < 0) i = -i; if (i >= n) i = 2 * n - 2 - i; return i; }

// K1: bilinear resize (2,3,1024,1024) -> (2,3,256,256), align-corners style
__global__ void k_resize(const float* __restrict__ img, float* __restrict__ x) {
    int idx = blockIdx.x * blockDim.x + threadIdx.x;
    if (idx >= 2 * 3 * 256 * 256) return;
    int ox = idx & 255;
    int oy = (idx >> 8) & 255;
    int bc = idx >> 16;  // [0,6)
    float py = oy * (1023.f / 255.f);
    float px = ox * (1023.f / 255.f);
    int iy0 = (int)floorf(py); if (iy0 > 1022) iy0 = 1022; float fy = py - (float)iy0;
    int ix0 = (int)floorf(px); if (ix0 > 1022) ix0 = 1022; float fx = px - (float)ix0;
    const float* p = img + (size_t)bc * 1024 * 1024;
    float a00 = p[iy0 * 1024 + ix0],       a01 = p[iy0 * 1024 + ix0 + 1];
    float a10 = p[(iy0 + 1) * 1024 + ix0], a11 = p[(iy0 + 1) * 1024 + ix0 + 1];
    float r0 = a00 + fy * (a10 - a00);  // interp along H (axis 2) first
    float r1 = a01 + fy * (a11 - a01);
    x[idx] = r0 + fx * (r1 - r0);
}

// 3x3 stride-2 reflect conv + SiLU, no K-split (conv1/conv2).
// Thread = PX_PER out-x pixels x OC_PER ocs. Weights in LDS (uniform reads).
template<int CIN, int HIN, int WIN, int COUT, int PX_PER, int OC_PER>
__global__ __launch_bounds__(256) void k_conv(const float* __restrict__ in,
                                              const float* __restrict__ w,
                                              const float* __restrict__ bias,
                                              float* __restrict__ out) {
    constexpr int HOUT = HIN / 2, WOUT = WIN / 2;
    constexpr int W_U = WOUT / PX_PER;
    constexpr int NPXU = 2 * HOUT * W_U;
    constexpr int NB_PX = NPXU / 256;
    constexpr int XSPAN = 2 * PX_PER + 1;

    __shared__ float sw[OC_PER * CIN * 9];
    const int tid = threadIdx.x;
    const int ocu = blockIdx.x / NB_PX;
    const int bpx = blockIdx.x % NB_PX;
    {
        const float* src = w + (size_t)(ocu * OC_PER) * CIN * 9;
        for (int i = tid; i < OC_PER * CIN * 9; i += 256) sw[i] = src[i];
    }
    __syncthreads();

    const int pxu = bpx * 256 + tid;
    const int oxu = pxu % W_U;
    const int oy  = (pxu / W_U) % HOUT;
    const int bb  = pxu / (W_U * HOUT);
    const int ox0 = oxu * PX_PER;

    int iy[3];
#pragma unroll
    for (int k = 0; k < 3; ++k) iy[k] = reflect_i(2 * oy + k - 1, HIN);
    int xs[XSPAN];
#pragma unroll
    for (int d = 0; d < XSPAN; ++d) xs[d] = reflect_i(2 * ox0 - 1 + d, WIN);

    float acc[OC_PER][PX_PER];
#pragma unroll
    for (int o = 0; o < OC_PER; ++o)
#pragma unroll
        for (int p = 0; p < PX_PER; ++p) acc[o][p] = 0.f;

    for (int ic = 0; ic < CIN; ++ic) {
        const float* ib = in + ((size_t)bb * CIN + ic) * HIN * WIN;
        float t[3][XSPAN];
#pragma unroll
        for (int ky = 0; ky < 3; ++ky) {
            const float* rp = ib + iy[ky] * WIN;
#pragma unroll
            for (int d = 0; d < XSPAN; ++d) t[ky][d] = rp[xs[d]];
        }
#pragma unroll
        for (int o = 0; o < OC_PER; ++o) {
            const float* wp = sw + ((size_t)o * CIN + ic) * 9;
            float wv[9];
#pragma unroll
            for (int j = 0; j < 9; ++j) wv[j] = wp[j];
#pragma unroll
            for (int p = 0; p < PX_PER; ++p)
#pragma unroll
                for (int ky = 0; ky < 3; ++ky)
#pragma unroll
                    for (int kx = 0; kx < 3; ++kx)
                        acc[o][p] = fmaf(t[ky][2 * p + kx], wv[ky * 3 + kx], acc[o][p]);
        }
    }

#pragma unroll
    for (int o = 0; o < OC_PER; ++o) {
        const int oc = ocu * OC_PER + o;
        float bv = bias[oc];
        float* op = out + (((size_t)bb * COUT + oc) * HOUT + oy) * WOUT + ox0;
        if (PX_PER == 4) {
            float4 v = make_float4(silu_f(acc[o][0] + bv), silu_f(acc[o][1] + bv),
                                   silu_f(acc[o][2] + bv), silu_f(acc[o][3] + bv));
            *(float4*)op = v;
        } else if (PX_PER == 2) {
            float2 v = make_float2(silu_f(acc[o][0] + bv), silu_f(acc[o][1] + bv));
            *(float2*)op = v;
        } else {
#pragma unroll
            for (int p = 0; p < PX_PER; ++p) op[p] = silu_f(acc[o][p] + bv);
        }
    }
}

// 3x3 stride-2 reflect conv + SiLU with wave-level 4-way K-split (conv3/conv4).
// Block = 256 thr = 4 waves. wave = kc (Cin quarter), lane = pixel.
// Weight LDS reads are wave-uniform broadcasts (padded stride 12 for 16B align);
// input loads coalesced (lane = consecutive ox in one plane).
template<int CIN, int HIN, int WIN, int COUT, int OC_PER>
__global__ __launch_bounds__(256) void k_conv_w4(const float* __restrict__ in,
                                                 const float* __restrict__ w,
                                                 const float* __restrict__ bias,
                                                 float* __restrict__ out) {
    constexpr int HOUT = HIN / 2, WOUT = WIN / 2;
    constexpr int NPXU = 2 * HOUT * WOUT;
    constexpr int NB_PX = NPXU / 64;
    constexpr int ICC = CIN / 4;

    __shared__ float sw[OC_PER * CIN * 12];
    __shared__ float sred[4][OC_PER][64];
    const int tid = threadIdx.x;
    const int ocu = blockIdx.x / NB_PX;
    const int bpx = blockIdx.x % NB_PX;
    {
        const float* src = w + (size_t)(ocu * OC_PER) * CIN * 9;
        for (int i = tid; i < OC_PER * CIN * 9; i += 256)
            sw[(i / 9) * 12 + (i % 9)] = src[i];
    }
    __syncthreads();

    const int kc = tid >> 6;
    const int lane = tid & 63;
    const int pxu = bpx * 64 + lane;
    const int ox = pxu % WOUT;
    const int oy = (pxu / WOUT) % HOUT;
    const int bb = pxu / (WOUT * HOUT);

    int iy[3], xs[3];
#pragma unroll
    for (int k = 0; k < 3; ++k) {
        iy[k] = reflect_i(2 * oy + k - 1, HIN);
        xs[k] = reflect_i(2 * ox + k - 1, WIN);
    }

    float acc[OC_PER];
#pragma unroll
    for (int o = 0; o < OC_PER; ++o) acc[o] = 0.f;

    for (int icl = 0; icl < ICC; ++icl) {
        const int ic = kc * ICC + icl;
        const float* ib = in + ((size_t)bb * CIN + ic) * HIN * WIN;
        float t[3][3];
#pragma unroll
        for (int ky = 0; ky < 3; ++ky) {
            const float* rp = ib + iy[ky] * WIN;
#pragma unroll
            for (int kx = 0; kx < 3; ++kx) t[ky][kx] = rp[xs[kx]];
        }
#pragma unroll
        for (int o = 0; o < OC_PER; ++o) {
            const float* wp = sw + ((size_t)o * CIN + ic) * 12;
            float wv[9];
#pragma unroll
            for (int j = 0; j < 9; ++j) wv[j] = wp[j];
#pragma unroll
            for (int ky = 0; ky < 3; ++ky)
#pragma unroll
                for (int kx = 0; kx < 3; ++kx)
                    acc[o] = fmaf(t[ky][kx], wv[ky * 3 + kx], acc[o]);
        }
    }

#pragma unroll
    for (int o = 0; o < OC_PER; ++o) sred[kc][o][lane] = acc[o];
    __syncthreads();
    if (kc < OC_PER) {
        const int o = kc;
        const int oc = ocu * OC_PER + o;
        float s = sred[0][o][lane] + sred[1][o][lane] + sred[2][o][lane] + sred[3][o][lane];
        out[(((size_t)bb * COUT + oc) * HOUT + oy) * WOUT + ox] = silu_f(s + bias[oc]);
    }
}

// K6: fused avg-pool + concat -> feat (2,480,8,8), float4 inner reads
__global__ void k_pool(const float* __restrict__ c1, const float* __restrict__ c2,
                       const float* __restrict__ c3, const float* __restrict__ c4,
                       float* __restrict__ feat) {
    int idx = blockIdx.x * blockDim.x + threadIdx.x;
    if (idx >= 2 * 480 * 64) return;
    int x = idx & 7;
    int y = (idx >> 3) & 7;
    int fc = (idx >> 6) % 480;
    int bb = idx / (480 * 64);
    const float* src; int C, HW, k, c;
    if (fc < 32)       { src = c1; C = 32;  HW = 128; k = 16; c = fc; }
    else if (fc < 96)  { src = c2; C = 64;  HW = 64;  k = 8;  c = fc - 32; }
    else if (fc < 224) { src = c3; C = 128; HW = 32;  k = 4;  c = fc - 96; }
    else               { src = c4; C = 256; HW = 16;  k = 2;  c = fc - 224; }
    const float* p = src + ((size_t)bb * C + c) * HW * HW + (y * k) * HW + x * k;
    float s = 0.f;
    if (k >= 4) {
        for (int i = 0; i < k; ++i) {
            const float4* r4 = (const float4*)(p + i * HW);
            for (int j = 0; j < k / 4; ++j) {
                float4 q = r4[j];
                s += q.x + q.y + q.z + q.w;
            }
        }
    } else {
        for (int i = 0; i < k; ++i)
            for (int j = 0; j < k; ++j) s += p[i * HW + j];
    }
    feat[idx] = s / (float)(k * k);
}

// K7: lin1 = 3x3 reflect conv 480->128 on 8x8 + SiLU.
// Block (512 thr = 8 waves) per (bb, oc). Lane = pixel; wave = 1/8 of ic range.
__global__ __launch_bounds__(512) void k_lin1(const float* __restrict__ feat,
                                              const float* __restrict__ w,
                                              const float* __restrict__ bias,
                                              float* __restrict__ h1) {
    __shared__ float sw[480 * 9];
    __shared__ float sred[8][64];
    const int tid = threadIdx.x;
    const int bb = blockIdx.x >> 7;
    const int oc = blockIdx.x & 127;
    {
        const float* src = w + (size_t)oc * 480 * 9;
        for (int i = tid; i < 480 * 9; i += 512) sw[i] = src[i];
    }
    const int wave = tid >> 6;
    const int lane = tid & 63;
    const int py = lane >> 3, px = lane & 7;
    int srcl[9];
#pragma unroll
    for (int ky = 0; ky < 3; ++ky)
#pragma unroll
        for (int kx = 0; kx < 3; ++kx)
            srcl[ky * 3 + kx] = reflect_i(py + ky - 1, 8) * 8 + reflect_i(px + kx - 1, 8);
    __syncthreads();

    const float* fp = feat + (size_t)bb * 480 * 64;
    float acc = 0.f;
    for (int ic = wave * 60; ic < wave * 60 + 60; ++ic) {
        float v = fp[ic * 64 + lane];
        const float* wp = sw + ic * 9;
#pragma unroll
        for (int j = 0; j < 9; ++j)
            acc = fmaf(__shfl(v, srcl[j], 64), wp[j], acc);
    }
    sred[wave][lane] = acc;
    __syncthreads();
    if (wave == 0) {
        float s = 0.f;
#pragma unroll
        for (int wv = 0; wv < 8; ++wv) s += sred[wv][lane];
        h1[((size_t)bb * 128 + oc) * 64 + lane] = silu_f(s + bias[oc]);
    }
}

// K8: lin2 = 1x1 conv 128->27 + sigmoid -> wl (2,27,8,8)
__global__ void k_lin2(const float* __restrict__ h1, const float* __restrict__ w,
                       const float* __restrict__ bias, float* __restrict__ wl) {
    int idx = blockIdx.x * blockDim.x + threadIdx.x;
    if (idx >= 2 * 27 * 64) return;
    int pix = idx & 63;
    int oc = (idx >> 6) % 27;
    int bb = idx / (27 * 64);
    const float* hp = h1 + (size_t)bb * 128 * 64 + pix;
    const float* wp = w + oc * 128;
    float sum = bias[oc];
    for (int ic = 0; ic < 128; ++ic) sum = fmaf(hp[ic * 64], wp[ic], sum);
    wl[((size_t)bb * 27 + oc) * 64 + pix] = sigmoid_f(sum);
}

// K9: fused bilinear-upsample of wl + LUT interp + weighted sum + clip.
__global__ __launch_bounds__(256) void k_apply(const float* __restrict__ img,
                                               const float* __restrict__ wl,
                                               const float* __restrict__ luts,
                                               float* __restrict__ out) {
    __shared__ float slut[9 * 256];
    __shared__ float swl[9 * 64];
    __shared__ float su[9 * 8];
    int tid = threadIdx.x;
    int bc = blockIdx.y;         // 0..5
    int bb = bc / 3, c = bc % 3;
    for (int i = tid; i < 9 * 256; i += 256) slut[i] = luts[c * 9 * 256 + i];
    for (int i = tid; i < 9 * 64; i += 256) swl[i] = wl[((size_t)bb * 27 + c * 9) * 64 + i];

    const size_t plane = (((size_t)bb * 3 + c) * 1024);
    int x0 = tid * 4;
    float fx[4]; int ix0[4];
#pragma unroll
    for (int p = 0; p < 4; ++p) {
        float pxf = (x0 + p) * (7.f / 1023.f);
        int i = (int)pxf; if (i > 6) i = 6;
        ix0[p] = i; fx[p] = pxf - (float)i;
    }

    for (int rr = 0; rr < 8; ++rr) {
        int h = blockIdx.x * 8 + rr;
        float py = h * (7.f / 1023.f);
        int iy0 = (int)py; if (iy0 > 6) iy0 = 6;
        float fy = py - (float)iy0;
        __syncthreads();  // prev row done reading su (and staging done on rr==0)
        if (tid < 72) {
            int k = tid >> 3, ixx = tid & 7;
            float s0 = swl[k * 64 + iy0 * 8 + ixx];
            float s1 = swl[k * 64 + iy0 * 8 + 8 + ixx];
            su[tid] = fmaf(fy, s1 - s0, s0);
        }
        __syncthreads();

        size_t base = (plane + h) * 1024;
        float4 v = ((const float4*)(img + base))[tid];
        float xin[4] = {v.x, v.y, v.z, v.w};
        float o[4];
#pragma unroll
        for (int p = 0; p < 4; ++p) {
            float pv = fminf(fmaxf(xin[p], 0.f), 1.f) * 255.f;
            int i0 = (int)pv; if (i0 > 254) i0 = 254;
            float fr = pv - (float)i0;
            float acc = 0.f;
#pragma unroll
            for (int k = 0; k < 9; ++k) {
                float s0 = su[k * 8 + ix0[p]];
                float s1 = su[k * 8 + ix0[p] + 1];
                float wt = fmaf(fx[p], s1 - s0, s0);
                float l0 = slut[k * 256 + i0];
                float l1 = slut[k * 256 + i0 + 1];
                acc = fmaf(wt, fmaf(fr, l1 - l0, l0), acc);
            }
            o[p] = fminf(fmaxf(acc, 0.f), 1.f);
        }
        ((float4*)(out + base))[tid] = make_float4(o[0], o[1], o[2], o[3]);
    }
}

extern "C" void kernel_launch(void* const* d_in, const int* in_sizes, int n_in,
                              void* d_out, int out_size, void* d_ws, size_t ws_size,
                              hipStream_t stream) {
    const float* img     = (const float*)d_in[0];
    const float* conv1_w = (const float*)d_in[1];
    const float* conv1_b = (const float*)d_in[2];
    const float* conv2_w = (const float*)d_in[3];
    const float* conv2_b = (const float*)d_in[4];
    const float* conv3_w = (const float*)d_in[5];
    const float* conv3_b = (const float*)d_in[6];
    const float* conv4_w = (const float*)d_in[7];
    const float* conv4_b = (const float*)d_in[8];
    const float* lin1_w  = (const float*)d_in[9];
    const float* lin1_b  = (const float*)d_in[10];
    const float* lin2_w  = (const float*)d_in[11];
    const float* lin2_b  = (const float*)d_in[12];
    const float* luts    = (const float*)d_in[13];
    float* out = (float*)d_out;

    float* ws = (float*)d_ws;
    float* x_rs = ws;            ws += 2 * 3 * 256 * 256;
    float* c1   = ws;            ws += 2 * 32 * 128 * 128;
    float* c2   = ws;            ws += 2 * 64 * 64 * 64;
    float* c3   = ws;            ws += 2 * 128 * 32 * 32;
    float* c4   = ws;            ws += 2 * 256 * 16 * 16;
    float* feat = ws;            ws += 2 * 480 * 8 * 8;
    float* h1   = ws;            ws += 2 * 128 * 8 * 8;
    float* wl   = ws;            ws += 2 * 27 * 8 * 8;

    const int B = 256;
    k_resize<<<(2 * 3 * 256 * 256 + B - 1) / B, B, 0, stream>>>(img, x_rs);
    // conv1: PX4 x OC2 -> (2*128*32/256) * 16 = 512 blocks
    k_conv<3, 256, 256, 32, 4, 2><<<512, B, 0, stream>>>(x_rs, conv1_w, conv1_b, c1);
    // conv2: PX2 x OC2 -> (2*64*32/256) * 32 = 512 blocks
    k_conv<32, 128, 128, 64, 2, 2><<<512, B, 0, stream>>>(c1, conv2_w, conv2_b, c2);
    // conv3: wave-split KC4, OC2 -> (2*32*32/64) * 64 = 2048 blocks
    k_conv_w4<64, 64, 64, 128, 2><<<2048, B, 0, stream>>>(c2, conv3_w, conv3_b, c3);
    // conv4: wave-split KC4, OC2 -> (2*16*16/64) * 128 = 1024 blocks
    k_conv_w4<128, 32, 32, 256, 2><<<1024, B, 0, stream>>>(c3, conv4_w, conv4_b, c4);
    k_pool<<<(2 * 480 * 64 + B - 1) / B, B, 0, stream>>>(c1, c2, c3, c4, feat);
    k_lin1<<<256, 512, 0, stream>>>(feat, lin1_w, lin1_b, h1);
    k_lin2<<<(2 * 27 * 64 + B - 1) / B, B, 0, stream>>>(h1, lin2_w, lin2_b, wl);
    dim3 agrid(128, 6);
    k_apply<<<agrid, B, 0, stream>>>(img, wl, luts, out);
}